// Round 1
// baseline (581.850 us; speedup 1.0000x reference)
//
#include <hip/hip_runtime.h>

#define NTOK 256
#define TT 128
#define DD 64
#define HH 8

typedef __bf16 bf16_t;
typedef bf16_t bf16x8 __attribute__((ext_vector_type(8)));
typedef bf16_t bf16x4 __attribute__((ext_vector_type(4)));
typedef float f32x4 __attribute__((ext_vector_type(4)));

__device__ __forceinline__ bf16x8 load_f32x8_as_bf16(const float* p) {
    float4 a = *reinterpret_cast<const float4*>(p);
    float4 b = *reinterpret_cast<const float4*>(p + 4);
    bf16x8 r;
    r[0] = (bf16_t)a.x; r[1] = (bf16_t)a.y; r[2] = (bf16_t)a.z; r[3] = (bf16_t)a.w;
    r[4] = (bf16_t)b.x; r[5] = (bf16_t)b.y; r[6] = (bf16_t)b.z; r[7] = (bf16_t)b.w;
    return r;
}

// ---------------------------------------------------------------------------
// Kernel 1: QKV projection, one block per (t,h), 256 threads = 4 waves.
// Wave w computes rows 64w..64w+63 (4 m-tiles of 16).
// Q,K written row-major [th][n][d] bf16; V written transposed [th][d][n] bf16.
// ---------------------------------------------------------------------------
__global__ __launch_bounds__(256, 2)
void qkv_kernel(const float* __restrict__ x,
                const float* __restrict__ Wq, const float* __restrict__ bq,
                const float* __restrict__ Wk, const float* __restrict__ bk,
                const float* __restrict__ Wv, const float* __restrict__ bv,
                bf16_t* __restrict__ q_ws, bf16_t* __restrict__ k_ws,
                bf16_t* __restrict__ vt_ws) {
    const int t    = blockIdx.x >> 3;
    const int h    = blockIdx.x & 7;
    const int wave = threadIdx.x >> 6;
    const int lane = threadIdx.x & 63;
    const int l15  = lane & 15, quad = lane >> 4;

    // A-fragments of x (rows for this wave), converted to bf16.
    // A[m = l15][k = quad*8 + j], k-tile kt covers k = 32*kt..32*kt+31
    bf16x8 ax[4][2];
#pragma unroll
    for (int mt = 0; mt < 4; ++mt) {
        int n = (wave * 4 + mt) * 16 + l15;
        const float* xp = x + ((size_t)n * TT + t) * DD;
#pragma unroll
        for (int kt = 0; kt < 2; ++kt)
            ax[mt][kt] = load_f32x8_as_bf16(xp + kt * 32 + quad * 8);
    }

    const size_t thbase = (size_t)blockIdx.x * (NTOK * DD);
    const float* Ws[3] = {Wq, Wk, Wv};
    const float* bs[3] = {bq, bk, bv};

#pragma unroll
    for (int mat = 0; mat < 3; ++mat) {
        // B-fragments: B[k][d] = W[h*64+d][k]  (W row-major (HD, D))
        bf16x8 bw[4][2];
        float bias[4];
#pragma unroll
        for (int dt = 0; dt < 4; ++dt) {
            int d = dt * 16 + l15;
            const float* wp = Ws[mat] + ((size_t)(h * DD + d)) * DD;
#pragma unroll
            for (int kt = 0; kt < 2; ++kt)
                bw[dt][kt] = load_f32x8_as_bf16(wp + kt * 32 + quad * 8);
            bias[dt] = bs[mat][h * DD + d];
        }
#pragma unroll
        for (int mt = 0; mt < 4; ++mt) {
            int mtile = wave * 4 + mt;
#pragma unroll
            for (int dt = 0; dt < 4; ++dt) {
                f32x4 acc = {0.f, 0.f, 0.f, 0.f};
#pragma unroll
                for (int kt = 0; kt < 2; ++kt)
                    acc = __builtin_amdgcn_mfma_f32_16x16x32_bf16(
                        ax[mt][kt], bw[dt][kt], acc, 0, 0, 0);
                if (mat < 2) {
                    bf16_t* dst = (mat == 0 ? q_ws : k_ws) + thbase;
#pragma unroll
                    for (int r = 0; r < 4; ++r) {
                        int n = mtile * 16 + quad * 4 + r;
                        dst[(size_t)n * DD + dt * 16 + l15] =
                            (bf16_t)(acc[r] + bias[dt]);
                    }
                } else {
                    // V transposed: vt[d][n]; 4 consecutive n pack into 8B
                    bf16x4 pk;
#pragma unroll
                    for (int r = 0; r < 4; ++r)
                        pk[r] = (bf16_t)(acc[r] + bias[dt]);
                    int d  = dt * 16 + l15;
                    int n0 = mtile * 16 + quad * 4;
                    *reinterpret_cast<bf16x4*>(vt_ws + thbase + (size_t)d * NTOK + n0) = pk;
                }
            }
        }
    }
}

// ---------------------------------------------------------------------------
// Kernel 2: attention, one block per (t,h), 256 threads = 4 waves.
// Wave w processes m-tiles {4w..4w+3} (16 query rows each):
//   S = QK^T (MFMA, C-layout regs) -> *scale*w -> softmax (quad shfl_xor)
//   -> P staged bf16 in per-wave LDS slice -> O = P V (MFMA) -> store.
// ---------------------------------------------------------------------------
__global__ __launch_bounds__(256, 2)
void attn_kernel(const float* __restrict__ aw,
                 const bf16_t* __restrict__ q_ws, const bf16_t* __restrict__ k_ws,
                 const bf16_t* __restrict__ vt_ws, float* __restrict__ out) {
    const int t    = blockIdx.x >> 3;
    const int h    = blockIdx.x & 7;
    const int wave = threadIdx.x >> 6;
    const int lane = threadIdx.x & 63;
    const int l15  = lane & 15, quad = lane >> 4;

    // per-wave P staging: 16 rows x 256 cols, +8 bf16 pad -> 2-way banks on b128
    __shared__ __align__(16) bf16_t ps[4][16][264];

    const size_t thbase = (size_t)blockIdx.x * (NTOK * DD);
    const bf16_t* qp = q_ws + thbase;
    const bf16_t* kp = k_ws + thbase;
    const bf16_t* vp = vt_ws + thbase;
    const float*  wp = aw + (size_t)blockIdx.x * ((size_t)NTOK * NTOK);

    for (int it = 0; it < 4; ++it) {
        const int mtile = wave * 4 + it;

        // Q A-frags for this m-tile
        bf16x8 aq[2];
#pragma unroll
        for (int kt = 0; kt < 2; ++kt)
            aq[kt] = *reinterpret_cast<const bf16x8*>(
                qp + (size_t)(mtile * 16 + l15) * DD + kt * 32 + quad * 8);

        // S = Q K^T : 16 n-tiles of C-frags
        f32x4 s[16];
#pragma unroll
        for (int j = 0; j < 16; ++j) s[j] = (f32x4){0.f, 0.f, 0.f, 0.f};
#pragma unroll
        for (int j = 0; j < 16; ++j) {
#pragma unroll
            for (int kt = 0; kt < 2; ++kt) {
                bf16x8 bk = *reinterpret_cast<const bf16x8*>(
                    kp + (size_t)(j * 16 + l15) * DD + kt * 32 + quad * 8);
                s[j] = __builtin_amdgcn_mfma_f32_16x16x32_bf16(aq[kt], bk, s[j], 0, 0, 0);
            }
        }

        // scale, elementwise weights, row max
        const float scale = 0.125f;  // 1/sqrt(64)
        float mx[4] = {-1e30f, -1e30f, -1e30f, -1e30f};
#pragma unroll
        for (int j = 0; j < 16; ++j) {
#pragma unroll
            for (int r = 0; r < 4; ++r) {
                float wv = wp[(size_t)(mtile * 16 + quad * 4 + r) * NTOK + j * 16 + l15];
                float v = s[j][r] * scale * wv;
                s[j][r] = v;
                mx[r] = fmaxf(mx[r], v);
            }
        }
        // row r lives in the 16 lanes of this quad: xor-reduce masks 1,2,4,8
#pragma unroll
        for (int r = 0; r < 4; ++r) {
#pragma unroll
            for (int m = 1; m < 16; m <<= 1)
                mx[r] = fmaxf(mx[r], __shfl_xor(mx[r], m, 64));
        }
        float sm[4] = {0.f, 0.f, 0.f, 0.f};
#pragma unroll
        for (int j = 0; j < 16; ++j) {
#pragma unroll
            for (int r = 0; r < 4; ++r) {
                float e = __expf(s[j][r] - mx[r]);
                s[j][r] = e;
                sm[r] += e;
            }
        }
#pragma unroll
        for (int r = 0; r < 4; ++r) {
#pragma unroll
            for (int m = 1; m < 16; m <<= 1)
                sm[r] += __shfl_xor(sm[r], m, 64);
            sm[r] = 1.f / sm[r];
        }

        // stage P (C-layout -> LDS, bf16)
#pragma unroll
        for (int j = 0; j < 16; ++j) {
#pragma unroll
            for (int r = 0; r < 4; ++r)
                ps[wave][quad * 4 + r][j * 16 + l15] = (bf16_t)(s[j][r] * sm[r]);
        }
        __syncthreads();

        // O = P V : A-frags from LDS, B-frags from transposed V in global
        f32x4 o[4];
#pragma unroll
        for (int dt = 0; dt < 4; ++dt) o[dt] = (f32x4){0.f, 0.f, 0.f, 0.f};
#pragma unroll
        for (int kt = 0; kt < 8; ++kt) {
            bf16x8 ap = *reinterpret_cast<const bf16x8*>(&ps[wave][l15][kt * 32 + quad * 8]);
#pragma unroll
            for (int dt = 0; dt < 4; ++dt) {
                bf16x8 bv = *reinterpret_cast<const bf16x8*>(
                    vp + (size_t)(dt * 16 + l15) * NTOK + kt * 32 + quad * 8);
                o[dt] = __builtin_amdgcn_mfma_f32_16x16x32_bf16(ap, bv, o[dt], 0, 0, 0);
            }
        }

        // out flat = (H,N,T,D) contiguous: out[((h*256 + n)*128 + t)*64 + d]
#pragma unroll
        for (int dt = 0; dt < 4; ++dt) {
#pragma unroll
            for (int r = 0; r < 4; ++r) {
                int n = mtile * 16 + quad * 4 + r;
                out[(((size_t)h * NTOK + n) * TT + t) * DD + dt * 16 + l15] = o[dt][r];
            }
        }
        __syncthreads();  // protect staging reuse next iteration
    }
}

extern "C" void kernel_launch(void* const* d_in, const int* in_sizes, int n_in,
                              void* d_out, int out_size, void* d_ws, size_t ws_size,
                              hipStream_t stream) {
    const float* x  = (const float*)d_in[0];
    const float* Wq = (const float*)d_in[1];
    const float* bq = (const float*)d_in[2];
    const float* Wk = (const float*)d_in[3];
    const float* bk = (const float*)d_in[4];
    const float* Wv = (const float*)d_in[5];
    const float* bv = (const float*)d_in[6];
    const float* aw = (const float*)d_in[7];
    float* out = (float*)d_out;

    const size_t per = (size_t)TT * HH * NTOK * DD;  // 16,777,216 elems
    bf16_t* q_ws  = (bf16_t*)d_ws;
    bf16_t* k_ws  = q_ws + per;
    bf16_t* vt_ws = k_ws + per;
    // ws use: 3 * per * 2B = 100.7 MB

    qkv_kernel<<<TT * HH, 256, 0, stream>>>(x, Wq, bq, Wk, bk, Wv, bv,
                                            q_ws, k_ws, vt_ws);
    attn_kernel<<<TT * HH, 256, 0, stream>>>(aw, q_ws, k_ws, vt_ws, out);
}